// Round 7
// baseline (124.235 us; speedup 1.0000x reference)
//
#include <hip/hip_runtime.h>
#include <cstdint>

#define BATCH  4
#define SLEN   4096
#define FDIM   64
#define KDIM   32
#define KSPLIT 8
#define CHUNK  (SLEN / KSPLIT)   // 512

typedef __attribute__((ext_vector_type(8))) short bf16x8;
typedef __attribute__((ext_vector_type(4))) float f32x4;

static __device__ __forceinline__ short f2bf(float f) {
    union { float f; unsigned u; } v; v.f = f;
    unsigned r = v.u + 0x7fffu + ((v.u >> 16) & 1u);   // RNE
    return (short)(r >> 16);
}
static __device__ __forceinline__ float bf2f(short s) {
    union { unsigned u; float f; } v;
    v.u = ((unsigned)(unsigned short)s) << 16;
    return v.f;
}
// pack2bf(a,b) -> uint, low short = bf16(a), high short = bf16(b), RNE.
static __device__ __forceinline__ unsigned pack2bf(float a, float b) {
    union { float f; unsigned u; } x, y; x.f = a; y.f = b;
    unsigned ra = x.u + 0x7fffu + ((x.u >> 16) & 1u);
    unsigned rb = y.u + 0x7fffu + ((y.u >> 16) & 1u);
    return __builtin_amdgcn_perm(rb, ra, 0x07060302u);  // {rb.hi, ra.hi}
}

// ---------------------------------------------------------------------------
// Fused prep: (a) M -> bf16 hi/lo Dekker split, (b) V = X@W (fp32),
// (c) Vt[b][f][s0 + perm(c)] = bf16(V[b][s0+c][f]).
// perm within each 32-key group: c = 16h + 4q + r  ->  slot = 8q + 4h + r.
// This is exactly the PV A-operand k-slot order (k = quad*8 + j, j<4 from
// sub-tile 0, j>=4 from sub-tile 1), so the attn V B-frag is ONE b128 read.
// ---------------------------------------------------------------------------
__global__ __launch_bounds__(256) void prep(const float4* __restrict__ M4,
                                            ushort4* __restrict__ H4,
                                            ushort4* __restrict__ L4,
                                            const float* __restrict__ X,
                                            const float4* __restrict__ W4,
                                            float4* __restrict__ V4,
                                            short* __restrict__ Vt) {
    const int blk = blockIdx.y * gridDim.x + blockIdx.x;   // 0..255
    // --- (a) split M: 2 float4 per thread ---
#pragma unroll
    for (int r = 0; r < 2; ++r) {
        int i = (blk * 2 + r) * 256 + threadIdx.x;         // [0, 131072)
        float4 m = M4[i];
        ushort4 h, l;
        h.x = (unsigned short)f2bf(m.x); l.x = (unsigned short)f2bf(m.x - bf2f((short)h.x));
        h.y = (unsigned short)f2bf(m.y); l.y = (unsigned short)f2bf(m.y - bf2f((short)h.y));
        h.z = (unsigned short)f2bf(m.z); l.z = (unsigned short)f2bf(m.z - bf2f((short)h.z));
        h.w = (unsigned short)f2bf(m.w); l.w = (unsigned short)f2bf(m.w - bf2f((short)h.w));
        H4[i] = h; L4[i] = l;
    }
    // --- (b)+(c) XW + transpose ---
    __shared__ float t[64][65];
    const int b  = blockIdx.y;
    const int s0 = blockIdx.x * 64;
    const int o4 = threadIdx.x & 15;
    const int rq = threadIdx.x >> 4;
#pragma unroll
    for (int half = 0; half < 4; ++half) {
        int r = half * 16 + rq;
        const float* __restrict__ xr = X + ((size_t)b * SLEN + s0 + r) * FDIM;
        float4 acc = make_float4(0.f, 0.f, 0.f, 0.f);
#pragma unroll
        for (int f = 0; f < FDIM; ++f) {
            float4 w = W4[f * 16 + o4];
            float  x = xr[f];
            acc.x = fmaf(x, w.x, acc.x);
            acc.y = fmaf(x, w.y, acc.y);
            acc.z = fmaf(x, w.z, acc.z);
            acc.w = fmaf(x, w.w, acc.w);
        }
        V4[((size_t)b * SLEN + s0 + r) * 16 + o4] = acc;
        t[r][o4 * 4 + 0] = acc.x;
        t[r][o4 * 4 + 1] = acc.y;
        t[r][o4 * 4 + 2] = acc.z;
        t[r][o4 * 4 + 3] = acc.w;
    }
    __syncthreads();
    const int c0 = threadIdx.x & 63;
    const int r0 = threadIdx.x >> 6;
    // slot within 32-group: 8*((c>>2)&3) + 4*((c>>4)&1) + (c&3)
    const int pc = (c0 & 32) | (((c0 >> 2) & 3) << 3) | (((c0 >> 4) & 1) << 2)
                 | (c0 & 3);
#pragma unroll
    for (int i = 0; i < 16; ++i) {
        int f = r0 + i * 4;
        Vt[((size_t)b * FDIM + f) * SLEN + s0 + pc] = f2bf(t[c0][f]);
    }
}

// ---------------------------------------------------------------------------
// Attention partials. Block = 4 waves = 128 queries (QT=2 per wave).
// 64-key steps, double-buffered LDS staging (one barrier per step):
//   K-hi/K-lo rows natural order, V rows pre-permuted -> all MFMA fragments
//   are single ds_read_b128.
// QK operand-swapped (A=K, B=Q): C = [key][q]; exp'd scores feed the PV
// A-operand directly (no LDS round-trip for P).
// Additive partials: p = exp(relu(s)) raw (max s ~72 < fp32 overflow).
// ---------------------------------------------------------------------------
__global__ __launch_bounds__(256) void attn_mfma(const short* __restrict__ Mhi,
                                                 const short* __restrict__ Mlo,
                                                 const short* __restrict__ Vt,
                                                 float* __restrict__ accP,
                                                 float* __restrict__ lP) {
    const int bid  = blockIdx.x;                 // 1024 blocks
    const int slab = (bid & 7) + 8 * (bid >> 8); // (b,ks) id, XCD-local
    const int qblk = (bid >> 3) & 31;
    const int b    = slab >> 3;
    const int ks   = slab & 7;

    const int tid  = threadIdx.x;
    const int wave = tid >> 6;
    const int lane = tid & 63;
    const int col  = lane & 15;
    const int quad = lane >> 4;
    const int qbase = qblk * 128 + wave * 32;
    const int k0    = ks * CHUNK;

    const short* __restrict__ Mbh = Mhi + (size_t)b * SLEN * KDIM;
    const short* __restrict__ Mbl = Mlo + (size_t)b * SLEN * KDIM;
    const short* __restrict__ Vb  = Vt  + (size_t)b * FDIM * SLEN;

    // Double-buffered staging. Row stride 40 shorts (80 B, b128-aligned).
    __shared__ short khi[2][64 * 40];            // 64 key rows (dims 0..31)
    __shared__ short klo[2][64 * 40];
    __shared__ short vsh[2][2][64 * 40];         // [buf][32-key half][f row]

    // Q fragments (B-operand: n = q, k = quad*8+j), from global, natural.
    bf16x8 Qh[2], Ql[2];
#pragma unroll
    for (int tq = 0; tq < 2; ++tq) {
        int qo = (qbase + tq * 16 + col) * KDIM + quad * 8;
        Qh[tq] = *(const bf16x8*)(Mbh + qo);
        Ql[tq] = *(const bf16x8*)(Mbl + qo);
    }

    f32x4 accf[2][4];
#pragma unroll
    for (int tq = 0; tq < 2; ++tq)
#pragma unroll
        for (int fg = 0; fg < 4; ++fg) accf[tq][fg] = (f32x4){0.f, 0.f, 0.f, 0.f};
    float lacc[2] = {0.f, 0.f};

    // Staging roles: thread t stages 4 x 16B chunks per step.
    const int srow  = tid >> 2;                  // 0..63
    const int spart = tid & 3;                   // 0..3

    // Prologue: stage step 0 into buffer 0.
    {
        bf16x8 rkh = *(const bf16x8*)(Mbh + (k0 + srow) * KDIM + spart * 8);
        bf16x8 rkl = *(const bf16x8*)(Mbl + (k0 + srow) * KDIM + spart * 8);
        bf16x8 rv0 = *(const bf16x8*)(Vb + (size_t)srow * SLEN + k0 + spart * 8);
        bf16x8 rv1 = *(const bf16x8*)(Vb + (size_t)srow * SLEN + k0 + 32 + spart * 8);
        *(bf16x8*)(khi[0]    + srow * 40 + spart * 8) = rkh;
        *(bf16x8*)(klo[0]    + srow * 40 + spart * 8) = rkl;
        *(bf16x8*)(vsh[0][0] + srow * 40 + spart * 8) = rv0;
        *(bf16x8*)(vsh[0][1] + srow * 40 + spart * 8) = rv1;
    }
    __syncthreads();

    int p = 0;
#pragma unroll 1
    for (int kt = k0; kt < k0 + CHUNK; kt += 64) {
        const int ktn  = kt + 64;
        const bool more = ktn < k0 + CHUNK;      // uniform
        bf16x8 nkh, nkl, nv0, nv1;
        if (more) {                              // prefetch next step
            nkh = *(const bf16x8*)(Mbh + (ktn + srow) * KDIM + spart * 8);
            nkl = *(const bf16x8*)(Mbl + (ktn + srow) * KDIM + spart * 8);
            nv0 = *(const bf16x8*)(Vb + (size_t)srow * SLEN + ktn + spart * 8);
            nv1 = *(const bf16x8*)(Vb + (size_t)srow * SLEN + ktn + 32 + spart * 8);
        }

        // ---- fragment loads from buffer p (all single b128) ----
        const short* __restrict__ KH = khi[p];
        const short* __restrict__ KL = klo[p];
        bf16x8 Kh[4], Kl[4];
#pragma unroll
        for (int t = 0; t < 4; ++t) {
            Kh[t] = *(const bf16x8*)(KH + (t * 16 + col) * 40 + quad * 8);
            Kl[t] = *(const bf16x8*)(KL + (t * 16 + col) * 40 + quad * 8);
        }
        bf16x8 Vv[4][2];
#pragma unroll
        for (int fg = 0; fg < 4; ++fg)
#pragma unroll
            for (int h = 0; h < 2; ++h)
                Vv[fg][h] = *(const bf16x8*)(vsh[p][h]
                                             + (fg * 16 + col) * 40 + quad * 8);

        // ---- QK + exp + PV, per q-tile ----
#pragma unroll
        for (int tq = 0; tq < 2; ++tq) {
            f32x4 z = (f32x4){0.f, 0.f, 0.f, 0.f};
            f32x4 c[4];
#pragma unroll
            for (int t = 0; t < 4; ++t) {
                c[t] = __builtin_amdgcn_mfma_f32_16x16x32_bf16(Kh[t], Ql[tq], z, 0, 0, 0);
                c[t] = __builtin_amdgcn_mfma_f32_16x16x32_bf16(Kl[t], Qh[tq], c[t], 0, 0, 0);
                c[t] = __builtin_amdgcn_mfma_f32_16x16x32_bf16(Kh[t], Qh[tq], c[t], 0, 0, 0);
            }
#pragma unroll
            for (int g = 0; g < 2; ++g) {        // 32-key groups
                float e0 = __expf(fmaxf(c[2 * g][0], 0.f));
                float e1 = __expf(fmaxf(c[2 * g][1], 0.f));
                float e2 = __expf(fmaxf(c[2 * g][2], 0.f));
                float e3 = __expf(fmaxf(c[2 * g][3], 0.f));
                float e4 = __expf(fmaxf(c[2 * g + 1][0], 0.f));
                float e5 = __expf(fmaxf(c[2 * g + 1][1], 0.f));
                float e6 = __expf(fmaxf(c[2 * g + 1][2], 0.f));
                float e7 = __expf(fmaxf(c[2 * g + 1][3], 0.f));
                lacc[tq] += ((e0 + e1) + (e2 + e3)) + ((e4 + e5) + (e6 + e7));

                union { unsigned u[4]; bf16x8 v; } pa;
                pa.u[0] = pack2bf(e0, e1);
                pa.u[1] = pack2bf(e2, e3);
                pa.u[2] = pack2bf(e4, e5);
                pa.u[3] = pack2bf(e6, e7);
#pragma unroll
                for (int fg = 0; fg < 4; ++fg)
                    accf[tq][fg] = __builtin_amdgcn_mfma_f32_16x16x32_bf16(
                        pa.v, Vv[fg][g], accf[tq][fg], 0, 0, 0);
            }
        }

        // ---- stage next step into the other buffer, single barrier ----
        if (more) {
            *(bf16x8*)(khi[p ^ 1]    + srow * 40 + spart * 8) = nkh;
            *(bf16x8*)(klo[p ^ 1]    + srow * 40 + spart * 8) = nkl;
            *(bf16x8*)(vsh[p ^ 1][0] + srow * 40 + spart * 8) = nv0;
            *(bf16x8*)(vsh[p ^ 1][1] + srow * 40 + spart * 8) = nv1;
        }
        __syncthreads();
        p ^= 1;
    }

    // Epilogue: O C-layout: q = qbase + tq*16 + quad*4 + j, f = fg*16 + col.
#pragma unroll
    for (int tq = 0; tq < 2; ++tq) {
#pragma unroll
        for (int j = 0; j < 4; ++j) {
            int q = qbase + tq * 16 + quad * 4 + j;
            size_t base = ((size_t)b * SLEN + q) * KSPLIT + ks;
            float* __restrict__ op = accP + base * FDIM;
#pragma unroll
            for (int fg = 0; fg < 4; ++fg)
                op[fg * 16 + col] = accf[tq][fg][j];
        }
        float lv = lacc[tq];
        lv += __shfl_xor(lv, 16);
        lv += __shfl_xor(lv, 32);
        if (quad == 0) {
            int q = qbase + tq * 16 + col;
            lP[((size_t)b * SLEN + q) * KSPLIT + ks] = lv;
        }
    }
}

// ---------------------------------------------------------------------------
// out = V + (sum acc_i)/(sum l_i) + bias, float4.
// ---------------------------------------------------------------------------
__global__ __launch_bounds__(256) void combine_kernel(const float4* __restrict__ V4,
                                                      const float4* __restrict__ accP4,
                                                      const float* __restrict__ lP,
                                                      const float4* __restrict__ bias4,
                                                      float4* __restrict__ out4) {
    int i  = blockIdx.x * 256 + threadIdx.x;     // [0, B*S*16)
    int o4 = i & 15;
    int row = i >> 4;
    float nx = 0.f, ny = 0.f, nz = 0.f, nw = 0.f, den = 0.f;
#pragma unroll
    for (int k = 0; k < KSPLIT; ++k) {
        float4 a = accP4[((size_t)row * KSPLIT + k) * 16 + o4];
        nx += a.x; ny += a.y; nz += a.z; nw += a.w;
        den += lP[(size_t)row * KSPLIT + k];
    }
    float r = 1.f / den;
    float4 v = V4[i];
    float4 bb = bias4[o4];
    float4 o;
    o.x = v.x + nx * r + bb.x;
    o.y = v.y + ny * r + bb.y;
    o.z = v.z + nz * r + bb.z;
    o.w = v.w + nw * r + bb.w;
    out4[i] = o;
}

// ---------------------------------------------------------------------------
extern "C" void kernel_launch(void* const* d_in, const int* in_sizes, int n_in,
                              void* d_out, int out_size, void* d_ws, size_t ws_size,
                              hipStream_t stream) {
    const float* X    = (const float*)d_in[0];   // [4,4096,64]
    const float* M    = (const float*)d_in[1];   // [4,4096,32]
    const float* W    = (const float*)d_in[2];   // [64,64]
    const float* bias = (const float*)d_in[3];   // [64]
    float* out = (float*)d_out;                  // [4,4096,64]

    const size_t vElems = (size_t)BATCH * SLEN * FDIM;   // 1,048,576
    const size_t mElems = (size_t)BATCH * SLEN * KDIM;   //   524,288
    const size_t rows   = (size_t)BATCH * SLEN;          //    16,384

    float* Vf   = (float*)d_ws;
    float* accP = Vf + vElems;
    float* lP   = accP + vElems * KSPLIT;
    short* Mhi  = (short*)(lP + rows * KSPLIT);
    short* Mlo  = Mhi + mElems;
    short* Vt   = Mlo + mElems;

    prep<<<dim3(SLEN / 64, BATCH), 256, 0, stream>>>(
        (const float4*)M, (ushort4*)Mhi, (ushort4*)Mlo,
        X, (const float4*)W, (float4*)Vf, Vt);

    attn_mfma<<<dim3((SLEN / 128) * BATCH * KSPLIT), 256, 0, stream>>>(
        Mhi, Mlo, Vt, accP, lP);

    combine_kernel<<<(int)(vElems / 1024), 256, 0, stream>>>(
        (const float4*)Vf, (const float4*)accP, lP, (const float4*)bias,
        (float4*)out);
}

// Round 8
// 124.046 us; speedup vs baseline: 1.0015x; 1.0015x over previous
//
#include <hip/hip_runtime.h>
#include <cstdint>

#define BATCH  4
#define SLEN   4096
#define FDIM   64
#define KDIM   32
#define KSPLIT 8
#define CHUNK  (SLEN / KSPLIT)   // 512

typedef __attribute__((ext_vector_type(8))) short bf16x8;
typedef __attribute__((ext_vector_type(4))) float f32x4;

static __device__ __forceinline__ short f2bf(float f) {
    union { float f; unsigned u; } v; v.f = f;
    unsigned r = v.u + 0x7fffu + ((v.u >> 16) & 1u);   // RNE
    return (short)(r >> 16);
}
static __device__ __forceinline__ float bf2f(short s) {
    union { unsigned u; float f; } v;
    v.u = ((unsigned)(unsigned short)s) << 16;
    return v.f;
}
// pack2bf(a,b) -> uint, low short = bf16(a), high short = bf16(b), RNE.
static __device__ __forceinline__ unsigned pack2bf(float a, float b) {
    union { float f; unsigned u; } x, y; x.f = a; y.f = b;
    unsigned ra = x.u + 0x7fffu + ((x.u >> 16) & 1u);
    unsigned rb = y.u + 0x7fffu + ((y.u >> 16) & 1u);
    return __builtin_amdgcn_perm(rb, ra, 0x07060302u);  // {rb.hi, ra.hi}
}

// ---------------------------------------------------------------------------
// Fused prep:
//  (a) M -> bf16 hi/lo Dekker split (K side, unscaled)
//      and (M*log2e) -> bf16 hi/lo (Q side, pre-scaled for exp2)
//  (b) V = X@W (fp32)
//  (c) Vt[b][f][s0 + perm(c)] = bf16(V[b][s0+c][f]); perm within each 32-key
//      group: c = 16h + 4q + r -> slot = 8q + 4h + r (PV A-operand k-order,
//      so the attn V B-frag is ONE ds_read_b128).
// ---------------------------------------------------------------------------
__global__ __launch_bounds__(256) void prep(const float4* __restrict__ M4,
                                            ushort4* __restrict__ H4,
                                            ushort4* __restrict__ L4,
                                            ushort4* __restrict__ QH4,
                                            ushort4* __restrict__ QL4,
                                            const float* __restrict__ X,
                                            const float4* __restrict__ W4,
                                            float4* __restrict__ V4,
                                            short* __restrict__ Vt) {
    const int blk = blockIdx.y * gridDim.x + blockIdx.x;   // 0..255
    const float LOG2E = 1.4426950408889634f;
#pragma unroll
    for (int r = 0; r < 2; ++r) {
        int i = (blk * 2 + r) * 256 + threadIdx.x;         // [0, 131072)
        float4 m = M4[i];
        ushort4 h, l, sh, sl;
        h.x = (unsigned short)f2bf(m.x); l.x = (unsigned short)f2bf(m.x - bf2f((short)h.x));
        h.y = (unsigned short)f2bf(m.y); l.y = (unsigned short)f2bf(m.y - bf2f((short)h.y));
        h.z = (unsigned short)f2bf(m.z); l.z = (unsigned short)f2bf(m.z - bf2f((short)h.z));
        h.w = (unsigned short)f2bf(m.w); l.w = (unsigned short)f2bf(m.w - bf2f((short)h.w));
        float sx = m.x * LOG2E, sy = m.y * LOG2E, sz = m.z * LOG2E, sw = m.w * LOG2E;
        sh.x = (unsigned short)f2bf(sx); sl.x = (unsigned short)f2bf(sx - bf2f((short)sh.x));
        sh.y = (unsigned short)f2bf(sy); sl.y = (unsigned short)f2bf(sy - bf2f((short)sh.y));
        sh.z = (unsigned short)f2bf(sz); sl.z = (unsigned short)f2bf(sz - bf2f((short)sh.z));
        sh.w = (unsigned short)f2bf(sw); sl.w = (unsigned short)f2bf(sw - bf2f((short)sh.w));
        H4[i] = h; L4[i] = l; QH4[i] = sh; QL4[i] = sl;
    }
    // --- (b)+(c) XW + transpose ---
    __shared__ float t[64][65];
    const int b  = blockIdx.y;
    const int s0 = blockIdx.x * 64;
    const int o4 = threadIdx.x & 15;
    const int rq = threadIdx.x >> 4;
#pragma unroll
    for (int half = 0; half < 4; ++half) {
        int r = half * 16 + rq;
        const float* __restrict__ xr = X + ((size_t)b * SLEN + s0 + r) * FDIM;
        float4 acc = make_float4(0.f, 0.f, 0.f, 0.f);
#pragma unroll
        for (int f = 0; f < FDIM; ++f) {
            float4 w = W4[f * 16 + o4];
            float  x = xr[f];
            acc.x = fmaf(x, w.x, acc.x);
            acc.y = fmaf(x, w.y, acc.y);
            acc.z = fmaf(x, w.z, acc.z);
            acc.w = fmaf(x, w.w, acc.w);
        }
        V4[((size_t)b * SLEN + s0 + r) * 16 + o4] = acc;
        t[r][o4 * 4 + 0] = acc.x;
        t[r][o4 * 4 + 1] = acc.y;
        t[r][o4 * 4 + 2] = acc.z;
        t[r][o4 * 4 + 3] = acc.w;
    }
    __syncthreads();
    const int c0 = threadIdx.x & 63;
    const int r0 = threadIdx.x >> 6;
    const int pc = (c0 & 32) | (((c0 >> 2) & 3) << 3) | (((c0 >> 4) & 1) << 2)
                 | (c0 & 3);
#pragma unroll
    for (int i = 0; i < 16; ++i) {
        int f = r0 + i * 4;
        Vt[((size_t)b * FDIM + f) * SLEN + s0 + pc] = f2bf(t[c0][f]);
    }
}

// ---------------------------------------------------------------------------
// Attention partials. Block = 4 waves = 256 queries (QT=4 per wave): the
// same 16 LDS frag-reads per step now feed 80 MFMAs (LDS-wire was the
// binding constraint at QT=2). Single-buffer staging, 2 barriers / 64-key
// step (best-measured R6 structure).
// QK operand-swapped (A=K, B=Q): C = [key][q]; exp'd scores feed the PV
// A-operand directly. Q is pre-scaled by log2e -> p = exp2(max(c,0)).
// Additive partials: max s*log2e ~ 104 < fp32 overflow.
// ---------------------------------------------------------------------------
__global__ __launch_bounds__(256, 2) void attn_mfma(const short* __restrict__ Mhi,
                                                    const short* __restrict__ Mlo,
                                                    const short* __restrict__ Qhi,
                                                    const short* __restrict__ Qlo,
                                                    const short* __restrict__ Vt,
                                                    float* __restrict__ accP,
                                                    float* __restrict__ lP) {
    const int bid  = blockIdx.x;                 // 512 blocks
    const int xcd  = bid & 7;
    const int slot = bid >> 3;                   // 0..63
    const int g    = xcd + 8 * (slot >> 4);      // slab (b,ks) id [0,32)
    const int qblk = slot & 15;                  // q-block [0,16)
    const int b    = g >> 3;
    const int ks   = g & 7;

    const int tid  = threadIdx.x;
    const int wave = tid >> 6;
    const int lane = tid & 63;
    const int col  = lane & 15;
    const int quad = lane >> 4;
    const int qbase = qblk * 256 + wave * 64;
    const int k0    = ks * CHUNK;

    const short* __restrict__ Mbh = Mhi + (size_t)b * SLEN * KDIM;
    const short* __restrict__ Mbl = Mlo + (size_t)b * SLEN * KDIM;
    const short* __restrict__ Qbh = Qhi + (size_t)b * SLEN * KDIM;
    const short* __restrict__ Qbl = Qlo + (size_t)b * SLEN * KDIM;
    const short* __restrict__ Vb  = Vt  + (size_t)b * FDIM * SLEN;

    // Single-buffer staging, 64 keys/step. Row stride 40 shorts (80 B).
    __shared__ short khi[64 * 40];               // 5120 B
    __shared__ short klo[64 * 40];
    __shared__ short vsh[2][64 * 40];            // [32-key half][f row]

    // Q fragments (B-operand: n = q, k = quad*8+j), scaled by log2e.
    bf16x8 Qh[4], Ql[4];
#pragma unroll
    for (int tq = 0; tq < 4; ++tq) {
        int qo = (qbase + tq * 16 + col) * KDIM + quad * 8;
        Qh[tq] = *(const bf16x8*)(Qbh + qo);
        Ql[tq] = *(const bf16x8*)(Qbl + qo);
    }

    f32x4 accf[4][4];
#pragma unroll
    for (int tq = 0; tq < 4; ++tq)
#pragma unroll
        for (int fg = 0; fg < 4; ++fg) accf[tq][fg] = (f32x4){0.f, 0.f, 0.f, 0.f};
    float lacc[4] = {0.f, 0.f, 0.f, 0.f};

    const int srow  = tid >> 2;                  // 0..63
    const int spart = tid & 3;                   // 0..3

#pragma unroll 1
    for (int kt = k0; kt < k0 + CHUNK; kt += 64) {
        // ---- stage 64 keys: K hi/lo + V both halves (4 b128 per thread) ----
        bf16x8 rkh = *(const bf16x8*)(Mbh + (kt + srow) * KDIM + spart * 8);
        bf16x8 rkl = *(const bf16x8*)(Mbl + (kt + srow) * KDIM + spart * 8);
        bf16x8 rv0 = *(const bf16x8*)(Vb + (size_t)srow * SLEN + kt + spart * 8);
        bf16x8 rv1 = *(const bf16x8*)(Vb + (size_t)srow * SLEN + kt + 32 + spart * 8);
        __syncthreads();                         // WAR vs previous consumers
        *(bf16x8*)(khi    + srow * 40 + spart * 8) = rkh;
        *(bf16x8*)(klo    + srow * 40 + spart * 8) = rkl;
        *(bf16x8*)(vsh[0] + srow * 40 + spart * 8) = rv0;
        *(bf16x8*)(vsh[1] + srow * 40 + spart * 8) = rv1;
        __syncthreads();                         // RAW

        // ---- Phase A: K frags + QK + exp2 -> packed P ----
        bf16x8 Kh[4], Kl[4];
#pragma unroll
        for (int t = 0; t < 4; ++t) {
            Kh[t] = *(const bf16x8*)(khi + (t * 16 + col) * 40 + quad * 8);
            Kl[t] = *(const bf16x8*)(klo + (t * 16 + col) * 40 + quad * 8);
        }
        bf16x8 paf[4][2];
#pragma unroll
        for (int tq = 0; tq < 4; ++tq) {
            f32x4 z = (f32x4){0.f, 0.f, 0.f, 0.f};
            f32x4 c[4];
#pragma unroll
            for (int t = 0; t < 4; ++t) {
                c[t] = __builtin_amdgcn_mfma_f32_16x16x32_bf16(Kh[t], Ql[tq], z, 0, 0, 0);
                c[t] = __builtin_amdgcn_mfma_f32_16x16x32_bf16(Kl[t], Qh[tq], c[t], 0, 0, 0);
                c[t] = __builtin_amdgcn_mfma_f32_16x16x32_bf16(Kh[t], Qh[tq], c[t], 0, 0, 0);
            }
#pragma unroll
            for (int gr = 0; gr < 2; ++gr) {     // 32-key groups
                float e0 = __builtin_amdgcn_exp2f(fmaxf(c[2 * gr][0], 0.f));
                float e1 = __builtin_amdgcn_exp2f(fmaxf(c[2 * gr][1], 0.f));
                float e2 = __builtin_amdgcn_exp2f(fmaxf(c[2 * gr][2], 0.f));
                float e3 = __builtin_amdgcn_exp2f(fmaxf(c[2 * gr][3], 0.f));
                float e4 = __builtin_amdgcn_exp2f(fmaxf(c[2 * gr + 1][0], 0.f));
                float e5 = __builtin_amdgcn_exp2f(fmaxf(c[2 * gr + 1][1], 0.f));
                float e6 = __builtin_amdgcn_exp2f(fmaxf(c[2 * gr + 1][2], 0.f));
                float e7 = __builtin_amdgcn_exp2f(fmaxf(c[2 * gr + 1][3], 0.f));
                lacc[tq] += ((e0 + e1) + (e2 + e3)) + ((e4 + e5) + (e6 + e7));
                union { unsigned u[4]; bf16x8 v; } pa;
                pa.u[0] = pack2bf(e0, e1);
                pa.u[1] = pack2bf(e2, e3);
                pa.u[2] = pack2bf(e4, e5);
                pa.u[3] = pack2bf(e6, e7);
                paf[tq][gr] = pa.v;
            }
        }

        // ---- Phase B: PV (V frag = one b128; shared across all 4 tq) ----
#pragma unroll
        for (int gr = 0; gr < 2; ++gr) {
#pragma unroll
            for (int fg = 0; fg < 4; ++fg) {
                bf16x8 Vv = *(const bf16x8*)(vsh[gr] + (fg * 16 + col) * 40
                                             + quad * 8);
#pragma unroll
                for (int tq = 0; tq < 4; ++tq)
                    accf[tq][fg] = __builtin_amdgcn_mfma_f32_16x16x32_bf16(
                        paf[tq][gr], Vv, accf[tq][fg], 0, 0, 0);
            }
        }
    }

    // Epilogue: O C-layout: q = qbase + tq*16 + quad*4 + j, f = fg*16 + col.
#pragma unroll
    for (int tq = 0; tq < 4; ++tq) {
#pragma unroll
        for (int j = 0; j < 4; ++j) {
            int q = qbase + tq * 16 + quad * 4 + j;
            size_t base = ((size_t)b * SLEN + q) * KSPLIT + ks;
            float* __restrict__ op = accP + base * FDIM;
#pragma unroll
            for (int fg = 0; fg < 4; ++fg)
                op[fg * 16 + col] = accf[tq][fg][j];
        }
        float lv = lacc[tq];
        lv += __shfl_xor(lv, 16);
        lv += __shfl_xor(lv, 32);
        if (quad == 0) {
            int q = qbase + tq * 16 + col;
            lP[((size_t)b * SLEN + q) * KSPLIT + ks] = lv;
        }
    }
}

// ---------------------------------------------------------------------------
// out = V + (sum acc_i)/(sum l_i) + bias, float4.
// ---------------------------------------------------------------------------
__global__ __launch_bounds__(256) void combine_kernel(const float4* __restrict__ V4,
                                                      const float4* __restrict__ accP4,
                                                      const float* __restrict__ lP,
                                                      const float4* __restrict__ bias4,
                                                      float4* __restrict__ out4) {
    int i  = blockIdx.x * 256 + threadIdx.x;     // [0, B*S*16)
    int o4 = i & 15;
    int row = i >> 4;
    float nx = 0.f, ny = 0.f, nz = 0.f, nw = 0.f, den = 0.f;
#pragma unroll
    for (int k = 0; k < KSPLIT; ++k) {
        float4 a = accP4[((size_t)row * KSPLIT + k) * 16 + o4];
        nx += a.x; ny += a.y; nz += a.z; nw += a.w;
        den += lP[(size_t)row * KSPLIT + k];
    }
    float r = 1.f / den;
    float4 v = V4[i];
    float4 bb = bias4[o4];
    float4 o;
    o.x = v.x + nx * r + bb.x;
    o.y = v.y + ny * r + bb.y;
    o.z = v.z + nz * r + bb.z;
    o.w = v.w + nw * r + bb.w;
    out4[i] = o;
}

// ---------------------------------------------------------------------------
extern "C" void kernel_launch(void* const* d_in, const int* in_sizes, int n_in,
                              void* d_out, int out_size, void* d_ws, size_t ws_size,
                              hipStream_t stream) {
    const float* X    = (const float*)d_in[0];   // [4,4096,64]
    const float* M    = (const float*)d_in[1];   // [4,4096,32]
    const float* W    = (const float*)d_in[2];   // [64,64]
    const float* bias = (const float*)d_in[3];   // [64]
    float* out = (float*)d_out;                  // [4,4096,64]

    const size_t vElems = (size_t)BATCH * SLEN * FDIM;   // 1,048,576
    const size_t mElems = (size_t)BATCH * SLEN * KDIM;   //   524,288
    const size_t rows   = (size_t)BATCH * SLEN;          //    16,384

    float* Vf   = (float*)d_ws;
    float* accP = Vf + vElems;
    float* lP   = accP + vElems * KSPLIT;
    short* Mhi  = (short*)(lP + rows * KSPLIT);
    short* Mlo  = Mhi + mElems;
    short* Qhi  = Mlo + mElems;
    short* Qlo  = Qhi + mElems;
    short* Vt   = Qlo + mElems;

    prep<<<dim3(SLEN / 64, BATCH), 256, 0, stream>>>(
        (const float4*)M, (ushort4*)Mhi, (ushort4*)Mlo,
        (ushort4*)Qhi, (ushort4*)Qlo,
        X, (const float4*)W, (float4*)Vf, Vt);

    attn_mfma<<<dim3((SLEN / 256) * BATCH * KSPLIT), 256, 0, stream>>>(
        Mhi, Mlo, Qhi, Qlo, Vt, accP, lP);

    combine_kernel<<<(int)(vElems / 1024), 256, 0, stream>>>(
        (const float4*)Vf, (const float4*)accP, lP, (const float4*)bias,
        (float4*)out);
}

// Round 9
// 122.501 us; speedup vs baseline: 1.0142x; 1.0126x over previous
//
#include <hip/hip_runtime.h>
#include <cstdint>

#define BATCH  4
#define SLEN   4096
#define FDIM   64
#define KDIM   32
#define KSPLIT 8
#define CHUNK  (SLEN / KSPLIT)   // 512

typedef __attribute__((ext_vector_type(8))) short bf16x8;
typedef __attribute__((ext_vector_type(4))) float f32x4;

static __device__ __forceinline__ short f2bf(float f) {
    union { float f; unsigned u; } v; v.f = f;
    unsigned r = v.u + 0x7fffu + ((v.u >> 16) & 1u);   // RNE
    return (short)(r >> 16);
}
static __device__ __forceinline__ float bf2f(short s) {
    union { unsigned u; float f; } v;
    v.u = ((unsigned)(unsigned short)s) << 16;
    return v.f;
}
// pack2bf(a,b) -> uint, low short = bf16(a), high short = bf16(b), RNE.
static __device__ __forceinline__ unsigned pack2bf(float a, float b) {
    union { float f; unsigned u; } x, y; x.f = a; y.f = b;
    unsigned ra = x.u + 0x7fffu + ((x.u >> 16) & 1u);
    unsigned rb = y.u + 0x7fffu + ((y.u >> 16) & 1u);
    return __builtin_amdgcn_perm(rb, ra, 0x07060302u);  // {rb.hi, ra.hi}
}

// ---------------------------------------------------------------------------
// Fused prep:
//  (a) M -> bf16 hi/lo Dekker split (K side, unscaled)
//      and (M*log2e) -> bf16 hi/lo (Q side, pre-scaled for exp2)
//  (b) V = X@W (fp32)
//  (c) Vt[b][f][s0 + perm(c)] = bf16(V[b][s0+c][f]); perm within each 32-key
//      group: c = 16h + 4q + r -> slot = 8q + 4h + r (PV A-operand k-order,
//      so the attn V B-frag is ONE ds_read_b128).
// ---------------------------------------------------------------------------
__global__ __launch_bounds__(256) void prep(const float4* __restrict__ M4,
                                            ushort4* __restrict__ H4,
                                            ushort4* __restrict__ L4,
                                            ushort4* __restrict__ QH4,
                                            ushort4* __restrict__ QL4,
                                            const float* __restrict__ X,
                                            const float4* __restrict__ W4,
                                            float4* __restrict__ V4,
                                            short* __restrict__ Vt) {
    const int blk = blockIdx.y * gridDim.x + blockIdx.x;   // 0..255
    const float LOG2E = 1.4426950408889634f;
#pragma unroll
    for (int r = 0; r < 2; ++r) {
        int i = (blk * 2 + r) * 256 + threadIdx.x;         // [0, 131072)
        float4 m = M4[i];
        ushort4 h, l, sh, sl;
        h.x = (unsigned short)f2bf(m.x); l.x = (unsigned short)f2bf(m.x - bf2f((short)h.x));
        h.y = (unsigned short)f2bf(m.y); l.y = (unsigned short)f2bf(m.y - bf2f((short)h.y));
        h.z = (unsigned short)f2bf(m.z); l.z = (unsigned short)f2bf(m.z - bf2f((short)h.z));
        h.w = (unsigned short)f2bf(m.w); l.w = (unsigned short)f2bf(m.w - bf2f((short)h.w));
        float sx = m.x * LOG2E, sy = m.y * LOG2E, sz = m.z * LOG2E, sw = m.w * LOG2E;
        sh.x = (unsigned short)f2bf(sx); sl.x = (unsigned short)f2bf(sx - bf2f((short)sh.x));
        sh.y = (unsigned short)f2bf(sy); sl.y = (unsigned short)f2bf(sy - bf2f((short)sh.y));
        sh.z = (unsigned short)f2bf(sz); sl.z = (unsigned short)f2bf(sz - bf2f((short)sh.z));
        sh.w = (unsigned short)f2bf(sw); sl.w = (unsigned short)f2bf(sw - bf2f((short)sh.w));
        H4[i] = h; L4[i] = l; QH4[i] = sh; QL4[i] = sl;
    }
    // --- (b)+(c) XW + transpose ---
    __shared__ float t[64][65];
    const int b  = blockIdx.y;
    const int s0 = blockIdx.x * 64;
    const int o4 = threadIdx.x & 15;
    const int rq = threadIdx.x >> 4;
#pragma unroll
    for (int half = 0; half < 4; ++half) {
        int r = half * 16 + rq;
        const float* __restrict__ xr = X + ((size_t)b * SLEN + s0 + r) * FDIM;
        float4 acc = make_float4(0.f, 0.f, 0.f, 0.f);
#pragma unroll
        for (int f = 0; f < FDIM; ++f) {
            float4 w = W4[f * 16 + o4];
            float  x = xr[f];
            acc.x = fmaf(x, w.x, acc.x);
            acc.y = fmaf(x, w.y, acc.y);
            acc.z = fmaf(x, w.z, acc.z);
            acc.w = fmaf(x, w.w, acc.w);
        }
        V4[((size_t)b * SLEN + s0 + r) * 16 + o4] = acc;
        t[r][o4 * 4 + 0] = acc.x;
        t[r][o4 * 4 + 1] = acc.y;
        t[r][o4 * 4 + 2] = acc.z;
        t[r][o4 * 4 + 3] = acc.w;
    }
    __syncthreads();
    const int c0 = threadIdx.x & 63;
    const int r0 = threadIdx.x >> 6;
    const int pc = (c0 & 32) | (((c0 >> 2) & 3) << 3) | (((c0 >> 4) & 1) << 2)
                 | (c0 & 3);
#pragma unroll
    for (int i = 0; i < 16; ++i) {
        int f = r0 + i * 4;
        Vt[((size_t)b * FDIM + f) * SLEN + s0 + pc] = f2bf(t[c0][f]);
    }
}

// ---------------------------------------------------------------------------
// Attention partials — R6 structure (best measured: 32-key steps, 10 KB LDS,
// 1024 blocks, high occupancy) with three VALU/latency trims:
//   * Q pre-scaled by log2e -> p = exp2(max(s,0)) (no per-score mul)
//   * l computed by an extra ones-B MFMA (idle matrix pipe) instead of
//     VALU adds + epilogue shuffles
//   * permuted Vt -> V B-frag is a single ds_read_b128
// QK operand-swapped (A=K, B=Q): C = [key][q]; exp'd scores feed the PV
// A-operand directly. Additive partials (max s*log2e ~104 < fp32 overflow).
// ---------------------------------------------------------------------------
__global__ __launch_bounds__(256, 4) void attn_mfma(const short* __restrict__ Mhi,
                                                    const short* __restrict__ Mlo,
                                                    const short* __restrict__ Qhi,
                                                    const short* __restrict__ Qlo,
                                                    const short* __restrict__ Vt,
                                                    float* __restrict__ accP,
                                                    float* __restrict__ lP) {
    const int bid  = blockIdx.x;                 // 1024 blocks
    const int slab = (bid & 7) + 8 * (bid >> 8); // (b,ks) id, XCD-local
    const int qblk = (bid >> 3) & 31;
    const int b    = slab >> 3;
    const int ks   = slab & 7;

    const int tid  = threadIdx.x;
    const int wave = tid >> 6;
    const int lane = tid & 63;
    const int col  = lane & 15;
    const int quad = lane >> 4;
    const int qbase = qblk * 128 + wave * 32;
    const int k0    = ks * CHUNK;

    const short* __restrict__ Mbh = Mhi + (size_t)b * SLEN * KDIM;
    const short* __restrict__ Mbl = Mlo + (size_t)b * SLEN * KDIM;
    const short* __restrict__ Qbh = Qhi + (size_t)b * SLEN * KDIM;
    const short* __restrict__ Qbl = Qlo + (size_t)b * SLEN * KDIM;
    const short* __restrict__ Vb  = Vt  + (size_t)b * FDIM * SLEN;

    __shared__ short khi[32 * 40];               // 2560 B each
    __shared__ short klo[32 * 40];
    __shared__ short vsh[64 * 40];               // 5120 B

    // Q fragments (B-operand: n = q, k = quad*8+j), pre-scaled by log2e.
    bf16x8 Qh[2], Ql[2];
#pragma unroll
    for (int tq = 0; tq < 2; ++tq) {
        int qo = (qbase + tq * 16 + col) * KDIM + quad * 8;
        Qh[tq] = *(const bf16x8*)(Qbh + qo);
        Ql[tq] = *(const bf16x8*)(Qbl + qo);
    }

    // ones B-fragment for the l-row-sum MFMA (bf16 1.0 = 0x3F80).
    const bf16x8 ONES = (bf16x8){0x3F80, 0x3F80, 0x3F80, 0x3F80,
                                 0x3F80, 0x3F80, 0x3F80, 0x3F80};

    f32x4 accf[2][4], accl[2];
#pragma unroll
    for (int tq = 0; tq < 2; ++tq) {
        accl[tq] = (f32x4){0.f, 0.f, 0.f, 0.f};
#pragma unroll
        for (int fg = 0; fg < 4; ++fg) accf[tq][fg] = (f32x4){0.f, 0.f, 0.f, 0.f};
    }

    // Staging roles (R6): tid<128 -> khi, tid>=128 -> klo; all -> vsh.
    const int krow  = (tid & 127) >> 2;          // 0..31
    const int kpart = tid & 3;
    const int vrow  = tid >> 2;                  // 0..63
    const short* __restrict__ Msrc = (tid < 128) ? Mbh : Mbl;
    short* __restrict__ kdst = (tid < 128) ? khi : klo;

#pragma unroll 1
    for (int kt = k0; kt < k0 + CHUNK; kt += 32) {
        bf16x8 kstg = *(const bf16x8*)(Msrc + (kt + krow) * KDIM + kpart * 8);
        bf16x8 vstg = *(const bf16x8*)(Vb + (size_t)vrow * SLEN + kt + kpart * 8);
        __syncthreads();                         // WAR vs previous consumers
        *(bf16x8*)(kdst + krow * 40 + kpart * 8) = kstg;
        *(bf16x8*)(vsh + vrow * 40 + kpart * 8)  = vstg;
        __syncthreads();                         // RAW

        // K A-frags (m = key) and V B-frags (single b128, permuted layout).
        bf16x8 Kh0 = *(const bf16x8*)(khi + col * 40 + quad * 8);
        bf16x8 Kh1 = *(const bf16x8*)(khi + (16 + col) * 40 + quad * 8);
        bf16x8 Kl0 = *(const bf16x8*)(klo + col * 40 + quad * 8);
        bf16x8 Kl1 = *(const bf16x8*)(klo + (16 + col) * 40 + quad * 8);
        bf16x8 Vv[4];
#pragma unroll
        for (int fg = 0; fg < 4; ++fg)
            Vv[fg] = *(const bf16x8*)(vsh + (fg * 16 + col) * 40 + quad * 8);

#pragma unroll
        for (int tq = 0; tq < 2; ++tq) {
            f32x4 z = (f32x4){0.f, 0.f, 0.f, 0.f};
            f32x4 c0 = __builtin_amdgcn_mfma_f32_16x16x32_bf16(Kh0, Ql[tq], z, 0, 0, 0);
            f32x4 c1 = __builtin_amdgcn_mfma_f32_16x16x32_bf16(Kh1, Ql[tq], z, 0, 0, 0);
            c0 = __builtin_amdgcn_mfma_f32_16x16x32_bf16(Kl0, Qh[tq], c0, 0, 0, 0);
            c1 = __builtin_amdgcn_mfma_f32_16x16x32_bf16(Kl1, Qh[tq], c1, 0, 0, 0);
            c0 = __builtin_amdgcn_mfma_f32_16x16x32_bf16(Kh0, Qh[tq], c0, 0, 0, 0);
            c1 = __builtin_amdgcn_mfma_f32_16x16x32_bf16(Kh1, Qh[tq], c1, 0, 0, 0);

            float e0 = __builtin_amdgcn_exp2f(fmaxf(c0[0], 0.f));
            float e1 = __builtin_amdgcn_exp2f(fmaxf(c0[1], 0.f));
            float e2 = __builtin_amdgcn_exp2f(fmaxf(c0[2], 0.f));
            float e3 = __builtin_amdgcn_exp2f(fmaxf(c0[3], 0.f));
            float e4 = __builtin_amdgcn_exp2f(fmaxf(c1[0], 0.f));
            float e5 = __builtin_amdgcn_exp2f(fmaxf(c1[1], 0.f));
            float e6 = __builtin_amdgcn_exp2f(fmaxf(c1[2], 0.f));
            float e7 = __builtin_amdgcn_exp2f(fmaxf(c1[3], 0.f));

            union { unsigned u[4]; bf16x8 v; } pa;
            pa.u[0] = pack2bf(e0, e1);
            pa.u[1] = pack2bf(e2, e3);
            pa.u[2] = pack2bf(e4, e5);
            pa.u[3] = pack2bf(e6, e7);

            accl[tq] = __builtin_amdgcn_mfma_f32_16x16x32_bf16(pa.v, ONES,
                                                               accl[tq], 0, 0, 0);
#pragma unroll
            for (int fg = 0; fg < 4; ++fg)
                accf[tq][fg] = __builtin_amdgcn_mfma_f32_16x16x32_bf16(
                    pa.v, Vv[fg], accf[tq][fg], 0, 0, 0);
        }
    }

    // Epilogue. C layout: row q = quad*4+j, col f = fg*16+col.
    // accl holds l in every column (ones-B) -> col 0 stores it, no shuffles.
#pragma unroll
    for (int tq = 0; tq < 2; ++tq) {
#pragma unroll
        for (int j = 0; j < 4; ++j) {
            int q = qbase + tq * 16 + quad * 4 + j;
            size_t base = ((size_t)b * SLEN + q) * KSPLIT + ks;
            float* __restrict__ op = accP + base * FDIM;
#pragma unroll
            for (int fg = 0; fg < 4; ++fg)
                op[fg * 16 + col] = accf[tq][fg][j];
            if (col == 0) lP[base] = accl[tq][j];
        }
    }
}

// ---------------------------------------------------------------------------
// out = V + (sum acc_i)/(sum l_i) + bias, float4.
// ---------------------------------------------------------------------------
__global__ __launch_bounds__(256) void combine_kernel(const float4* __restrict__ V4,
                                                      const float4* __restrict__ accP4,
                                                      const float* __restrict__ lP,
                                                      const float4* __restrict__ bias4,
                                                      float4* __restrict__ out4) {
    int i  = blockIdx.x * 256 + threadIdx.x;     // [0, B*S*16)
    int o4 = i & 15;
    int row = i >> 4;
    float nx = 0.f, ny = 0.f, nz = 0.f, nw = 0.f, den = 0.f;
#pragma unroll
    for (int k = 0; k < KSPLIT; ++k) {
        float4 a = accP4[((size_t)row * KSPLIT + k) * 16 + o4];
        nx += a.x; ny += a.y; nz += a.z; nw += a.w;
        den += lP[(size_t)row * KSPLIT + k];
    }
    float r = 1.f / den;
    float4 v = V4[i];
    float4 bb = bias4[o4];
    float4 o;
    o.x = v.x + nx * r + bb.x;
    o.y = v.y + ny * r + bb.y;
    o.z = v.z + nz * r + bb.z;
    o.w = v.w + nw * r + bb.w;
    out4[i] = o;
}

// ---------------------------------------------------------------------------
extern "C" void kernel_launch(void* const* d_in, const int* in_sizes, int n_in,
                              void* d_out, int out_size, void* d_ws, size_t ws_size,
                              hipStream_t stream) {
    const float* X    = (const float*)d_in[0];   // [4,4096,64]
    const float* M    = (const float*)d_in[1];   // [4,4096,32]
    const float* W    = (const float*)d_in[2];   // [64,64]
    const float* bias = (const float*)d_in[3];   // [64]
    float* out = (float*)d_out;                  // [4,4096,64]

    const size_t vElems = (size_t)BATCH * SLEN * FDIM;   // 1,048,576
    const size_t mElems = (size_t)BATCH * SLEN * KDIM;   //   524,288
    const size_t rows   = (size_t)BATCH * SLEN;          //    16,384

    float* Vf   = (float*)d_ws;
    float* accP = Vf + vElems;
    float* lP   = accP + vElems * KSPLIT;
    short* Mhi  = (short*)(lP + rows * KSPLIT);
    short* Mlo  = Mhi + mElems;
    short* Qhi  = Mlo + mElems;
    short* Qlo  = Qhi + mElems;
    short* Vt   = Qlo + mElems;

    prep<<<dim3(SLEN / 64, BATCH), 256, 0, stream>>>(
        (const float4*)M, (ushort4*)Mhi, (ushort4*)Mlo,
        (ushort4*)Qhi, (ushort4*)Qlo,
        X, (const float4*)W, (float4*)Vf, Vt);

    attn_mfma<<<dim3((SLEN / 128) * BATCH * KSPLIT), 256, 0, stream>>>(
        Mhi, Mlo, Qhi, Qlo, Vt, accP, lP);

    combine_kernel<<<(int)(vElems / 1024), 256, 0, stream>>>(
        (const float4*)Vf, (const float4*)accP, lP, (const float4*)bias,
        (float4*)out);
}